// Round 4
// baseline (382.624 us; speedup 1.0000x reference)
//
#include <hip/hip_runtime.h>
#include <math.h>

typedef __bf16 bf16;
typedef __bf16 bf16x8 __attribute__((ext_vector_type(8)));
typedef float f32x4 __attribute__((ext_vector_type(4)));

#define CC 256
#define BB 16
#define HH 56
#define WW 56
#define HWSZ 3136   // 56*56
#define EPS 1e-5f

// ws byte offsets
#define OFF_SCALE 0
#define OFF_SUMS  16384
#define OFF_WBF1  32768
#define OFF_WBF2  163840
#define OFF_WDW   294912        // 35*256 bf16 = 17920 B (wcomb 25 | wxz 5 | wyz 5)
#define OFF_BNC   312832        // 8*256 f32 = 8192 B
#define OFF_OUT2  321024        // NEL bf16

// ---------------------------------------------------------------------------
// K0: precast weights -> bf16, build combined DW taps + BN consts, zero sums.
// grid 257 blocks x 256.
// ---------------------------------------------------------------------------
__global__ __launch_bounds__(256) void precast(
    const float* __restrict__ w1, const float* __restrict__ w2,
    const float* __restrict__ xy3, const float* __restrict__ xy5,
    const float* __restrict__ xz3, const float* __restrict__ xz5,
    const float* __restrict__ yz3, const float* __restrict__ yz5,
    const float* __restrict__ gxy, const float* __restrict__ bxy,
    const float* __restrict__ mxy, const float* __restrict__ vxy,
    const float* __restrict__ gxz, const float* __restrict__ bxz,
    const float* __restrict__ mxz, const float* __restrict__ vxz,
    const float* __restrict__ gyz, const float* __restrict__ byz,
    const float* __restrict__ myz, const float* __restrict__ vyz,
    const float* __restrict__ alpha, const float* __restrict__ beta,
    bf16* __restrict__ wbf1, bf16* __restrict__ wbf2,
    bf16* __restrict__ wdw, float* __restrict__ bnc,
    float* __restrict__ sums)
{
    const int blk = blockIdx.x, t = threadIdx.x;
    if (blk < 128) {
        int i = blk * 512 + t * 2;
        wbf1[i] = (bf16)w1[i]; wbf1[i + 1] = (bf16)w1[i + 1];
    } else if (blk < 256) {
        int i = (blk - 128) * 512 + t * 2;
        wbf2[i] = (bf16)w2[i]; wbf2[i + 1] = (bf16)w2[i + 1];
    } else {
        const int c = t;
#pragma unroll
        for (int dh = 0; dh < 5; ++dh)
#pragma unroll
            for (int dw = 0; dw < 5; ++dw) {
                float v = xy5[c * 25 + dh * 5 + dw];
                if (dh >= 1 && dh <= 3 && dw >= 1 && dw <= 3)
                    v += xy3[c * 9 + (dh - 1) * 3 + (dw - 1)];
                wdw[(dh * 5 + dw) * CC + c] = (bf16)v;
            }
#pragma unroll
        for (int d = 0; d < 5; ++d) {
            float v = xz5[c * 5 + d];
            if (d >= 1 && d <= 3) v += xz3[c * 3 + d - 1];
            wdw[(25 + d) * CC + c] = (bf16)v;
            float u = yz5[c * 5 + d];
            if (d >= 1 && d <= 3) u += yz3[c * 3 + d - 1];
            wdw[(30 + d) * CC + c] = (bf16)u;
        }
        float s;
        s = gxy[c] * rsqrtf(vxy[c] + EPS); bnc[0*CC+c] = s; bnc[1*CC+c] = bxy[c] - mxy[c]*s;
        s = gxz[c] * rsqrtf(vxz[c] + EPS); bnc[2*CC+c] = s; bnc[3*CC+c] = bxz[c] - mxz[c]*s;
        s = gyz[c] * rsqrtf(vyz[c] + EPS); bnc[4*CC+c] = s; bnc[5*CC+c] = byz[c] - myz[c]*s;
        bnc[6*CC+c] = alpha[c]; bnc[7*CC+c] = beta[c];
        for (int i = t; i < BB * CC; i += 256) sums[i] = 0.f;
    }
}

// ---------------------------------------------------------------------------
// K1: pw1 GEMM, NCHW fp32 in -> NHWC bf16 out.  mid[b][hw][co].
// Block tile: 64 hw x 128 co, K=256. grid (49,2,16), 4 waves split hw.
// X transposed into LDS (coalesced staging); W fragments direct from L1/L2.
// ---------------------------------------------------------------------------
__global__ __launch_bounds__(256) void pw_gemm1(
    const float* __restrict__ in, const bf16* __restrict__ wbf,
    bf16* __restrict__ mid)
{
    __shared__ __align__(16) bf16 XT[64][264];   // [hw][ci]
    const int hw0 = blockIdx.x * 64;
    const int co0 = blockIdx.y * 128;
    const int b   = blockIdx.z;
    const int t   = threadIdx.x;

    // coalesced staging: lane group of 4 covers 64B of one ci row
    {
        const int ci_lo = t >> 2;          // 0..63
        const int g     = t & 3;
        const float* base = in + (size_t)b * CC * HWSZ + hw0;
#pragma unroll
        for (int p = 0; p < 4; ++p) {
            const int ci = p * 64 + ci_lo;
            const float* row = base + (size_t)ci * HWSZ;
#pragma unroll
            for (int ch = 0; ch < 4; ++ch) {
                const int hw = ch * 16 + g * 4;
                f32x4 v = *(const f32x4*)(row + hw);
#pragma unroll
                for (int j = 0; j < 4; ++j) XT[hw + j][ci] = (bf16)v[j];
            }
        }
    }
    __syncthreads();

    const int lane = t & 63, wv = t >> 6;
    const int q = lane >> 4, m = lane & 15;

    bf16x8 afr[8];
#pragma unroll
    for (int kk = 0; kk < 8; ++kk)
        afr[kk] = *(const bf16x8*)(&XT[wv * 16 + m][kk * 32 + q * 8]);

    bf16* ob = mid + ((size_t)b * HWSZ + hw0 + wv * 16) * CC;
#pragma unroll
    for (int n = 0; n < 8; ++n) {
        f32x4 acc = {};
        const bf16* bb = wbf + (size_t)(co0 + n * 16 + m) * CC + q * 8;
#pragma unroll
        for (int kk = 0; kk < 8; ++kk) {
            bf16x8 bfr = *(const bf16x8*)(bb + kk * 32);
            acc = __builtin_amdgcn_mfma_f32_16x16x32_bf16(afr[kk], bfr, acc, 0, 0, 0);
        }
        const int co = co0 + n * 16 + m;
#pragma unroll
        for (int r = 0; r < 4; ++r)
            ob[(size_t)(q * 4 + r) * CC + co] = (bf16)acc[r];
    }
}

// ---------------------------------------------------------------------------
// K2: fused depthwise + BN + ReLU + gate, NHWC, no data LDS.
// Thread = 8 channels of one pixel; 25 vector tap loads feed all 3 branches.
// grid (7, 56, 16): block = 8 consecutive w, all 256 c.
// ---------------------------------------------------------------------------
__global__ __launch_bounds__(256) void dwfuse(
    const bf16* __restrict__ mid, const bf16* __restrict__ wdw,
    const float* __restrict__ bnc, bf16* __restrict__ top)
{
    __shared__ bf16  lw[35 * 256];
    __shared__ float lbn[8 * 256];
    const int t = threadIdx.x;
    for (int i = t; i < 35 * 256; i += 256) lw[i] = wdw[i];
    for (int i = t; i < 8 * 256; i += 256) lbn[i] = bnc[i];
    __syncthreads();

    const int w = blockIdx.x * 8 + (t >> 5);
    const int h = blockIdx.y;
    const int b = blockIdx.z;
    const int c0 = (t & 31) * 8;
    const size_t plane = (size_t)b * HWSZ;

    float axy[8] = {}, axz[8] = {}, ayz[8] = {};
#pragma unroll
    for (int dh = 0; dh < 5; ++dh) {
        const int hh = h + dh - 2;
        const bool okh = (unsigned)hh < (unsigned)HH;
#pragma unroll
        for (int dw = 0; dw < 5; ++dw) {
            const int ww2 = w + dw - 2;
            if (okh && (unsigned)ww2 < (unsigned)WW) {
                bf16x8 v = *(const bf16x8*)(mid + ((plane + hh * WW + ww2) * CC + c0));
                bf16x8 wc = *(const bf16x8*)(&lw[(dh * 5 + dw) * 256 + c0]);
#pragma unroll
                for (int j = 0; j < 8; ++j) {
                    const float fv = (float)v[j];
                    axy[j] += (float)wc[j] * fv;
                }
                if (dh == 2) {
                    bf16x8 wz = *(const bf16x8*)(&lw[(25 + dw) * 256 + c0]);
#pragma unroll
                    for (int j = 0; j < 8; ++j) axz[j] += (float)wz[j] * (float)v[j];
                }
                if (dw == 2) {
                    bf16x8 wy = *(const bf16x8*)(&lw[(30 + dh) * 256 + c0]);
#pragma unroll
                    for (int j = 0; j < 8; ++j) ayz[j] += (float)wy[j] * (float)v[j];
                }
            }
        }
    }

    bf16x8 r;
#pragma unroll
    for (int j = 0; j < 8; ++j) {
        const int c = c0 + j;
        const float fxy = fmaxf(axy[j] * lbn[c]         + lbn[256 + c], 0.f);
        const float fxz = fmaxf(axz[j] * lbn[2*256 + c] + lbn[3*256 + c], 0.f);
        const float fyz = fmaxf(ayz[j] * lbn[4*256 + c] + lbn[5*256 + c], 0.f);
        const float z   = lbn[6*256 + c] * fxz + lbn[7*256 + c] * fyz;
        const float g   = 1.f / (1.f + expf(-z));
        r[j] = (bf16)fmaxf(fxy * g, 0.f);
    }
    *(bf16x8*)(top + ((plane + h * WW + w) * CC + c0)) = r;
}

// ---------------------------------------------------------------------------
// K3: pw2 GEMM (NHWC in/out, zero LDS) + BN + ReLU + SE partial sums.
// Block tile 64 hw x 128 co. grid (49,2,16).
// ---------------------------------------------------------------------------
__global__ __launch_bounds__(256) void pw_gemm2(
    const bf16* __restrict__ top, const bf16* __restrict__ wbf,
    const float* __restrict__ g2, const float* __restrict__ b2,
    const float* __restrict__ m2, const float* __restrict__ v2,
    bf16* __restrict__ out2, float* __restrict__ sums)
{
    const int hw0 = blockIdx.x * 64;
    const int co0 = blockIdx.y * 128;
    const int b   = blockIdx.z;
    const int t   = threadIdx.x;
    const int lane = t & 63, wv = t >> 6;
    const int q = lane >> 4, m = lane & 15;

    const bf16* ap = top + ((size_t)b * HWSZ + hw0 + wv * 16 + m) * CC;
    bf16x8 afr[8];
#pragma unroll
    for (int kk = 0; kk < 8; ++kk)
        afr[kk] = *(const bf16x8*)(ap + kk * 32 + q * 8);

    bf16* ob = out2 + ((size_t)b * HWSZ + hw0 + wv * 16) * CC;
#pragma unroll
    for (int n = 0; n < 8; ++n) {
        f32x4 acc = {};
        const bf16* bb = wbf + (size_t)(co0 + n * 16 + m) * CC + q * 8;
#pragma unroll
        for (int kk = 0; kk < 8; ++kk) {
            bf16x8 bfr = *(const bf16x8*)(bb + kk * 32);
            acc = __builtin_amdgcn_mfma_f32_16x16x32_bf16(afr[kk], bfr, acc, 0, 0, 0);
        }
        const int co = co0 + n * 16 + m;
        const float sc = g2[co] * rsqrtf(v2[co] + EPS);
        const float sh = b2[co] - m2[co] * sc;
        float rs = 0.f;
#pragma unroll
        for (int r = 0; r < 4; ++r) {
            float v = fmaxf(acc[r] * sc + sh, 0.f);
            rs += v;
            ob[(size_t)(q * 4 + r) * CC + co] = (bf16)v;
        }
        rs += __shfl_xor(rs, 16);
        rs += __shfl_xor(rs, 32);
        if (q == 0) atomicAdd(&sums[b * CC + co], rs);
    }
}

// ---------------------------------------------------------------------------
// K4: SE fully-connected: scale[b,c] = sigmoid(W2 relu(W1 mean + b1) + b2)
// ---------------------------------------------------------------------------
__global__ __launch_bounds__(256) void se_fc(
    const float* __restrict__ sums,
    const float* __restrict__ w1, const float* __restrict__ b1,
    const float* __restrict__ w2, const float* __restrict__ b2,
    float* __restrict__ scale)
{
    __shared__ float mean[256];
    __shared__ float hid[16];
    const int b = blockIdx.x, tid = threadIdx.x;
    mean[tid] = sums[b * CC + tid] * (1.f / (float)HWSZ);
    __syncthreads();
    if (tid < 16) {
        float h = b1[tid];
        for (int cd = 0; cd < 256; ++cd) h += w1[tid * 256 + cd] * mean[cd];
        hid[tid] = fmaxf(h, 0.f);
    }
    __syncthreads();
    float v = b2[tid];
#pragma unroll
    for (int md = 0; md < 16; ++md) v += w2[tid * 16 + md] * hid[md];
    scale[b * CC + tid] = 1.f / (1.f + expf(-v));
}

// ---------------------------------------------------------------------------
// K5: out[b][c][hw] = out2[b][hw][c] * scale[b,c] + x[b][c][hw]
// 64x64 LDS tile transpose.  grid (49, 4, 16).
// ---------------------------------------------------------------------------
__global__ __launch_bounds__(256) void se_apply(
    const bf16* __restrict__ out2, const float* __restrict__ x,
    const float* __restrict__ scale, float* __restrict__ out)
{
    __shared__ float TT[64 * 68];   // [c_local][hw_local], pad 68
    const int hw0 = blockIdx.x * 64;
    const int c0  = blockIdx.y * 64;
    const int b   = blockIdx.z;
    const int t   = threadIdx.x;

    {
        const int hw_r = t >> 2;
        const int coff = (t & 3) * 16;
        const bf16* p = out2 + ((size_t)b * HWSZ + hw0 + hw_r) * CC + c0 + coff;
        bf16x8 u0 = *(const bf16x8*)(p);
        bf16x8 u1 = *(const bf16x8*)(p + 8);
        const float* sp = scale + b * CC + c0 + coff;
        f32x4 s0 = *(const f32x4*)(sp), s1 = *(const f32x4*)(sp + 4);
        f32x4 s2 = *(const f32x4*)(sp + 8), s3 = *(const f32x4*)(sp + 12);
#pragma unroll
        for (int j = 0; j < 4; ++j) {
            TT[(coff + j)      * 68 + hw_r] = (float)u0[j]     * s0[j];
            TT[(coff + 4 + j)  * 68 + hw_r] = (float)u0[4 + j] * s1[j];
            TT[(coff + 8 + j)  * 68 + hw_r] = (float)u1[j]     * s2[j];
            TT[(coff + 12 + j) * 68 + hw_r] = (float)u1[4 + j] * s3[j];
        }
    }
    __syncthreads();
    {
        const int c_r   = t >> 2;
        const int hwoff = (t & 3) * 16;
        const size_t go = ((size_t)b * CC + c0 + c_r) * HWSZ + hw0 + hwoff;
#pragma unroll
        for (int v = 0; v < 4; ++v) {
            f32x4 tv = *(const f32x4*)(&TT[c_r * 68 + hwoff + v * 4]);
            f32x4 xv = *(const f32x4*)(x + go + v * 4);
#pragma unroll
            for (int j = 0; j < 4; ++j) tv[j] += xv[j];
            *(f32x4*)(out + go + v * 4) = tv;
        }
    }
}

// ---------------------------------------------------------------------------
extern "C" void kernel_launch(void* const* d_in, const int* in_sizes, int n_in,
                              void* d_out, int out_size, void* d_ws, size_t ws_size,
                              hipStream_t stream)
{
    const float* x      = (const float*)d_in[0];
    const float* pw1_w  = (const float*)d_in[1];
    const float* xy3_w  = (const float*)d_in[2];
    const float* xy5_w  = (const float*)d_in[3];
    const float* bnxy_g = (const float*)d_in[4];
    const float* bnxy_b = (const float*)d_in[5];
    const float* bnxy_m = (const float*)d_in[6];
    const float* bnxy_v = (const float*)d_in[7];
    const float* xz3_w  = (const float*)d_in[8];
    const float* xz5_w  = (const float*)d_in[9];
    const float* bnxz_g = (const float*)d_in[10];
    const float* bnxz_b = (const float*)d_in[11];
    const float* bnxz_m = (const float*)d_in[12];
    const float* bnxz_v = (const float*)d_in[13];
    const float* yz3_w  = (const float*)d_in[14];
    const float* yz5_w  = (const float*)d_in[15];
    const float* bnyz_g = (const float*)d_in[16];
    const float* bnyz_b = (const float*)d_in[17];
    const float* bnyz_m = (const float*)d_in[18];
    const float* bnyz_v = (const float*)d_in[19];
    const float* alpha  = (const float*)d_in[20];
    const float* beta   = (const float*)d_in[21];
    const float* pw2_w  = (const float*)d_in[22];
    const float* bn2_g  = (const float*)d_in[23];
    const float* bn2_b  = (const float*)d_in[24];
    const float* bn2_m  = (const float*)d_in[25];
    const float* bn2_v  = (const float*)d_in[26];
    const float* fc1_w  = (const float*)d_in[27];
    const float* fc1_b  = (const float*)d_in[28];
    const float* fc2_w  = (const float*)d_in[29];
    const float* fc2_b  = (const float*)d_in[30];

    const size_t NEL = (size_t)BB * CC * HWSZ;   // 12,845,056
    char* ws = (char*)d_ws;
    float* scale = (float*)(ws + OFF_SCALE);
    float* sums  = (float*)(ws + OFF_SUMS);
    bf16*  wbf1  = (bf16*) (ws + OFF_WBF1);
    bf16*  wbf2  = (bf16*) (ws + OFF_WBF2);
    bf16*  wdw   = (bf16*) (ws + OFF_WDW);
    float* bnc   = (float*)(ws + OFF_BNC);
    bf16*  out2  = (bf16*) (ws + OFF_OUT2);
    bf16*  mid   = (bf16*)d_out;           // d_out as scratch: mid | top
    bf16*  top   = (bf16*)d_out + NEL;

    precast<<<257, 256, 0, stream>>>(pw1_w, pw2_w,
        xy3_w, xy5_w, xz3_w, xz5_w, yz3_w, yz5_w,
        bnxy_g, bnxy_b, bnxy_m, bnxy_v,
        bnxz_g, bnxz_b, bnxz_m, bnxz_v,
        bnyz_g, bnyz_b, bnyz_m, bnyz_v,
        alpha, beta, wbf1, wbf2, wdw, bnc, sums);

    dim3 gg(49, 2, 16);
    pw_gemm1<<<gg, 256, 0, stream>>>(x, wbf1, mid);
    dwfuse<<<dim3(7, 56, 16), 256, 0, stream>>>(mid, wdw, bnc, top);
    pw_gemm2<<<gg, 256, 0, stream>>>(top, wbf2, bn2_g, bn2_b, bn2_m, bn2_v,
                                     out2, sums);
    se_fc<<<BB, 256, 0, stream>>>(sums, fc1_w, fc1_b, fc2_w, fc2_b, scale);
    se_apply<<<dim3(49, 4, 16), 256, 0, stream>>>(out2, x, scale, (float*)d_out);
}

// Round 6
// 321.256 us; speedup vs baseline: 1.1910x; 1.1910x over previous
//
#include <hip/hip_runtime.h>
#include <math.h>

typedef __bf16 bf16;
typedef __bf16 bf16x8 __attribute__((ext_vector_type(8)));
typedef __bf16 bf16x4 __attribute__((ext_vector_type(4)));
typedef float f32x4 __attribute__((ext_vector_type(4)));

#define CC 256
#define BB 16
#define HH 56
#define WW 56
#define HWSZ 3136   // 56*56
#define EPS 1e-5f

// ws byte offsets
#define OFF_SCALE 0
#define OFF_SUMS  16384
#define OFF_WBF1  32768
#define OFF_WBF2  163840
#define OFF_WDW   294912        // 35*256 bf16 (wcomb 25 | wxz 5 | wyz 5)
#define OFF_BNC   312832        // 8*256 f32
#define OFF_OUT2  321024        // NEL bf16

// ---------------------------------------------------------------------------
// K0: precast weights -> bf16, combined DW taps + BN consts, zero sums.
// ---------------------------------------------------------------------------
__global__ __launch_bounds__(256) void precast(
    const float* __restrict__ w1, const float* __restrict__ w2,
    const float* __restrict__ xy3, const float* __restrict__ xy5,
    const float* __restrict__ xz3, const float* __restrict__ xz5,
    const float* __restrict__ yz3, const float* __restrict__ yz5,
    const float* __restrict__ gxy, const float* __restrict__ bxy,
    const float* __restrict__ mxy, const float* __restrict__ vxy,
    const float* __restrict__ gxz, const float* __restrict__ bxz,
    const float* __restrict__ mxz, const float* __restrict__ vxz,
    const float* __restrict__ gyz, const float* __restrict__ byz,
    const float* __restrict__ myz, const float* __restrict__ vyz,
    const float* __restrict__ alpha, const float* __restrict__ beta,
    bf16* __restrict__ wbf1, bf16* __restrict__ wbf2,
    bf16* __restrict__ wdw, float* __restrict__ bnc,
    float* __restrict__ sums)
{
    const int blk = blockIdx.x, t = threadIdx.x;
    if (blk < 128) {
        int i = blk * 512 + t * 2;
        wbf1[i] = (bf16)w1[i]; wbf1[i + 1] = (bf16)w1[i + 1];
    } else if (blk < 256) {
        int i = (blk - 128) * 512 + t * 2;
        wbf2[i] = (bf16)w2[i]; wbf2[i + 1] = (bf16)w2[i + 1];
    } else {
        const int c = t;
#pragma unroll
        for (int dh = 0; dh < 5; ++dh)
#pragma unroll
            for (int dw = 0; dw < 5; ++dw) {
                float v = xy5[c * 25 + dh * 5 + dw];
                if (dh >= 1 && dh <= 3 && dw >= 1 && dw <= 3)
                    v += xy3[c * 9 + (dh - 1) * 3 + (dw - 1)];
                wdw[(dh * 5 + dw) * CC + c] = (bf16)v;
            }
#pragma unroll
        for (int d = 0; d < 5; ++d) {
            float v = xz5[c * 5 + d];
            if (d >= 1 && d <= 3) v += xz3[c * 3 + d - 1];
            wdw[(25 + d) * CC + c] = (bf16)v;
            float u = yz5[c * 5 + d];
            if (d >= 1 && d <= 3) u += yz3[c * 3 + d - 1];
            wdw[(30 + d) * CC + c] = (bf16)u;
        }
        float s;
        s = gxy[c] * rsqrtf(vxy[c] + EPS); bnc[0*CC+c] = s; bnc[1*CC+c] = bxy[c] - mxy[c]*s;
        s = gxz[c] * rsqrtf(vxz[c] + EPS); bnc[2*CC+c] = s; bnc[3*CC+c] = bxz[c] - mxz[c]*s;
        s = gyz[c] * rsqrtf(vyz[c] + EPS); bnc[4*CC+c] = s; bnc[5*CC+c] = byz[c] - myz[c]*s;
        bnc[6*CC+c] = alpha[c]; bnc[7*CC+c] = beta[c];
        for (int i = t; i < BB * CC; i += 256) sums[i] = 0.f;
    }
}

// ---------------------------------------------------------------------------
// K1: pw1 GEMM.  mid[b][hw][co] = sum_ci x[b][ci][hw] * w[co][ci]  (bf16 out)
// Block: 64 hw x 256 co, 4 waves (wave = 64 co x 64 hw). grid (49, 16).
// A-frag = W row (contiguous, L2); B-frag = XT row (ds_read_b128).
// Staging: 4x4 register transpose + ds_write_b64.
// ---------------------------------------------------------------------------
__global__ __launch_bounds__(256) void pw_gemm1(
    const float* __restrict__ in, const bf16* __restrict__ wbf,
    bf16* __restrict__ mid)
{
    __shared__ __align__(16) bf16 XT[64][264];   // [hw][ci], pad 264
    const int hw0 = blockIdx.x * 64;
    const int b   = blockIdx.y;
    const int t   = threadIdx.x;

    {   // stage x tile (fp32 NCHW) -> XT[hw][ci] bf16
        const int hwg = (t & 15) * 4;
        const int cig = (t >> 4) * 4;
        const float* base = in + (size_t)b * CC * HWSZ + hw0 + hwg;
#pragma unroll
        for (int pass = 0; pass < 4; ++pass) {
            const int ci0 = pass * 64 + cig;
            f32x4 v[4];
#pragma unroll
            for (int i = 0; i < 4; ++i)
                v[i] = *(const f32x4*)(base + (size_t)(ci0 + i) * HWSZ);
#pragma unroll
            for (int j = 0; j < 4; ++j) {
                bf16x4 r = {(bf16)v[0][j], (bf16)v[1][j], (bf16)v[2][j], (bf16)v[3][j]};
                *(bf16x4*)(&XT[hwg + j][ci0]) = r;
            }
        }
    }
    __syncthreads();

    const int lane = t & 63, wv = t >> 6;
    const int q = lane >> 4, n = lane & 15;
    const int co_w = wv * 64;

    const bf16* wp[4];
#pragma unroll
    for (int cf = 0; cf < 4; ++cf)
        wp[cf] = wbf + (size_t)(co_w + cf * 16 + n) * CC + q * 8;

    f32x4 acc[4][4] = {};   // [cf][hf]
#pragma unroll
    for (int kk = 0; kk < 8; ++kk) {
        bf16x8 aq[4], bq[4];
#pragma unroll
        for (int cf = 0; cf < 4; ++cf) aq[cf] = *(const bf16x8*)(wp[cf] + kk * 32);
#pragma unroll
        for (int hf = 0; hf < 4; ++hf)
            bq[hf] = *(const bf16x8*)(&XT[hf * 16 + n][kk * 32 + q * 8]);
#pragma unroll
        for (int cf = 0; cf < 4; ++cf)
#pragma unroll
            for (int hf = 0; hf < 4; ++hf)
                acc[cf][hf] = __builtin_amdgcn_mfma_f32_16x16x32_bf16(
                    aq[cf], bq[hf], acc[cf][hf], 0, 0, 0);
    }

    bf16* ob = mid + ((size_t)b * HWSZ + hw0) * CC;
#pragma unroll
    for (int cf = 0; cf < 4; ++cf) {
        const int co4 = co_w + cf * 16 + q * 4;
#pragma unroll
        for (int hf = 0; hf < 4; ++hf) {
            bf16x4 r = {(bf16)acc[cf][hf][0], (bf16)acc[cf][hf][1],
                        (bf16)acc[cf][hf][2], (bf16)acc[cf][hf][3]};
            *(bf16x4*)(ob + (size_t)(hf * 16 + n) * CC + co4) = r;
        }
    }
}

// ---------------------------------------------------------------------------
// K2: fused depthwise + BN + ReLU + gate, NHWC. 2 h-rows per thread.
// grid (7, 28, 16); block 256 = 8 w x 32 c-groups.
// ---------------------------------------------------------------------------
__global__ __launch_bounds__(256) void dwfuse(
    const bf16* __restrict__ mid, const bf16* __restrict__ wdw,
    const float* __restrict__ bnc, bf16* __restrict__ top)
{
    __shared__ __align__(16) bf16  lw[35 * 256];
    __shared__ __align__(16) float lbn[8 * 256];
    const int t = threadIdx.x;
    for (int i = t; i < 35 * 256; i += 256) lw[i] = wdw[i];
    for (int i = t; i < 8 * 256; i += 256) lbn[i] = bnc[i];
    __syncthreads();

    const int w  = blockIdx.x * 8 + (t >> 5);
    const int h0 = blockIdx.y * 2;
    const int b  = blockIdx.z;
    const int c0 = (t & 31) * 8;
    const size_t plane = (size_t)b * HWSZ;

    float axy[2][8] = {}, axz[2][8] = {}, ayz[2][8] = {};
#pragma unroll
    for (int dhh = 0; dhh < 6; ++dhh) {          // hh = h0-2+dhh
        const int hh = h0 - 2 + dhh;
        if ((unsigned)hh >= (unsigned)HH) continue;
#pragma unroll
        for (int dw = 0; dw < 5; ++dw) {
            const int ww = w + dw - 2;
            if ((unsigned)ww >= (unsigned)WW) continue;
            bf16x8 v = *(const bf16x8*)(mid + ((plane + hh * WW + ww) * CC + c0));
            float fv[8];
#pragma unroll
            for (int j = 0; j < 8; ++j) fv[j] = (float)v[j];
#pragma unroll
            for (int p = 0; p < 2; ++p) {
                const int dh = dhh - p;          // tap row for pixel h0+p
                if (dh < 0 || dh > 4) continue;  // compile-time
                bf16x8 wc = *(const bf16x8*)(&lw[(dh * 5 + dw) * 256 + c0]);
#pragma unroll
                for (int j = 0; j < 8; ++j) axy[p][j] += (float)wc[j] * fv[j];
                if (dh == 2) {
                    bf16x8 wz = *(const bf16x8*)(&lw[(25 + dw) * 256 + c0]);
#pragma unroll
                    for (int j = 0; j < 8; ++j) axz[p][j] += (float)wz[j] * fv[j];
                }
                if (dw == 2) {
                    bf16x8 wy = *(const bf16x8*)(&lw[(30 + dh) * 256 + c0]);
#pragma unroll
                    for (int j = 0; j < 8; ++j) ayz[p][j] += (float)wy[j] * fv[j];
                }
            }
        }
    }

#pragma unroll
    for (int p = 0; p < 2; ++p) {
        bf16x8 r;
#pragma unroll
        for (int j = 0; j < 8; ++j) {
            const int c = c0 + j;
            const float fxy = fmaxf(axy[p][j] * lbn[c]         + lbn[256 + c], 0.f);
            const float fxz = fmaxf(axz[p][j] * lbn[2*256 + c] + lbn[3*256 + c], 0.f);
            const float fyz = fmaxf(ayz[p][j] * lbn[4*256 + c] + lbn[5*256 + c], 0.f);
            const float z   = lbn[6*256 + c] * fxz + lbn[7*256 + c] * fyz;
            const float g   = 1.f / (1.f + expf(-z));
            r[j] = (bf16)fmaxf(fxy * g, 0.f);
        }
        *(bf16x8*)(top + ((plane + (h0 + p) * WW + w) * CC + c0)) = r;
    }
}

// ---------------------------------------------------------------------------
// K3: pw2 GEMM + BN + ReLU + SE partial sums.  Same frame as K1, copy staging.
// ---------------------------------------------------------------------------
__global__ __launch_bounds__(256) void pw_gemm2(
    const bf16* __restrict__ top, const bf16* __restrict__ wbf,
    const float* __restrict__ g2, const float* __restrict__ b2,
    const float* __restrict__ m2, const float* __restrict__ v2,
    bf16* __restrict__ out2, float* __restrict__ sums)
{
    __shared__ __align__(16) bf16 XT[64][264];
    const int hw0 = blockIdx.x * 64;
    const int b   = blockIdx.y;
    const int t   = threadIdx.x;

    {   // straight copy staging (already NHWC): 64 bf16 per thread
        const int hw_r = t >> 2;
        const int k0   = (t & 3) * 64;
        const bf16* src = top + ((size_t)b * HWSZ + hw0 + hw_r) * CC + k0;
#pragma unroll
        for (int j = 0; j < 8; ++j)
            *(bf16x8*)(&XT[hw_r][k0 + j * 8]) = *(const bf16x8*)(src + j * 8);
    }
    __syncthreads();

    const int lane = t & 63, wv = t >> 6;
    const int q = lane >> 4, n = lane & 15;
    const int co_w = wv * 64;

    const bf16* wp[4];
#pragma unroll
    for (int cf = 0; cf < 4; ++cf)
        wp[cf] = wbf + (size_t)(co_w + cf * 16 + n) * CC + q * 8;

    f32x4 acc[4][4] = {};
#pragma unroll
    for (int kk = 0; kk < 8; ++kk) {
        bf16x8 aq[4], bq[4];
#pragma unroll
        for (int cf = 0; cf < 4; ++cf) aq[cf] = *(const bf16x8*)(wp[cf] + kk * 32);
#pragma unroll
        for (int hf = 0; hf < 4; ++hf)
            bq[hf] = *(const bf16x8*)(&XT[hf * 16 + n][kk * 32 + q * 8]);
#pragma unroll
        for (int cf = 0; cf < 4; ++cf)
#pragma unroll
            for (int hf = 0; hf < 4; ++hf)
                acc[cf][hf] = __builtin_amdgcn_mfma_f32_16x16x32_bf16(
                    aq[cf], bq[hf], acc[cf][hf], 0, 0, 0);
    }

    bf16* ob = out2 + ((size_t)b * HWSZ + hw0) * CC;
#pragma unroll
    for (int cf = 0; cf < 4; ++cf) {
        const int co4 = co_w + cf * 16 + q * 4;
        f32x4 g = *(const f32x4*)(g2 + co4);
        f32x4 bb = *(const f32x4*)(b2 + co4);
        f32x4 mm = *(const f32x4*)(m2 + co4);
        f32x4 vv = *(const f32x4*)(v2 + co4);
        f32x4 sc, sh;
#pragma unroll
        for (int r = 0; r < 4; ++r) {
            sc[r] = g[r] * rsqrtf(vv[r] + EPS);
            sh[r] = bb[r] - mm[r] * sc[r];
        }
        f32x4 rs = {};
#pragma unroll
        for (int hf = 0; hf < 4; ++hf) {
            bf16x4 r4;
#pragma unroll
            for (int r = 0; r < 4; ++r) {
                float v = fmaxf(acc[cf][hf][r] * sc[r] + sh[r], 0.f);
                rs[r] += v;
                r4[r] = (bf16)v;
            }
            *(bf16x4*)(ob + (size_t)(hf * 16 + n) * CC + co4) = r4;
        }
        // reduce over the 16 lanes (n) sharing this (q, co4)
#pragma unroll
        for (int msk = 1; msk < 16; msk <<= 1)
#pragma unroll
            for (int r = 0; r < 4; ++r) rs[r] += __shfl_xor(rs[r], msk);
        if (n == 0) {
#pragma unroll
            for (int r = 0; r < 4; ++r)
                atomicAdd(&sums[b * CC + co4 + r], rs[r]);
        }
    }
}

// ---------------------------------------------------------------------------
// K4: SE fully-connected: scale[b,c] = sigmoid(W2 relu(W1 mean + b1) + b2)
// ---------------------------------------------------------------------------
__global__ __launch_bounds__(256) void se_fc(
    const float* __restrict__ sums,
    const float* __restrict__ w1, const float* __restrict__ b1,
    const float* __restrict__ w2, const float* __restrict__ b2,
    float* __restrict__ scale)
{
    __shared__ float mean[256];
    __shared__ float hid[16];
    const int b = blockIdx.x, tid = threadIdx.x;
    mean[tid] = sums[b * CC + tid] * (1.f / (float)HWSZ);
    __syncthreads();
    if (tid < 16) {
        float h = b1[tid];
        for (int cd = 0; cd < 256; ++cd) h += w1[tid * 256 + cd] * mean[cd];
        hid[tid] = fmaxf(h, 0.f);
    }
    __syncthreads();
    float v = b2[tid];
#pragma unroll
    for (int md = 0; md < 16; ++md) v += w2[tid * 16 + md] * hid[md];
    scale[b * CC + tid] = 1.f / (1.f + expf(-v));
}

// ---------------------------------------------------------------------------
// K5: out[b][c][hw] = out2[b][hw][c] * scale[b,c] + x[b][c][hw]
// 64x64 LDS tile transpose.  grid (49, 4, 16).
// ---------------------------------------------------------------------------
__global__ __launch_bounds__(256) void se_apply(
    const bf16* __restrict__ out2, const float* __restrict__ x,
    const float* __restrict__ scale, float* __restrict__ out)
{
    __shared__ float TT[64 * 68];   // [c_local][hw_local], pad 68
    const int hw0 = blockIdx.x * 64;
    const int c0  = blockIdx.y * 64;
    const int b   = blockIdx.z;
    const int t   = threadIdx.x;

    {
        const int hw_r = t >> 2;
        const int coff = (t & 3) * 16;
        const bf16* p = out2 + ((size_t)b * HWSZ + hw0 + hw_r) * CC + c0 + coff;
        bf16x8 u0 = *(const bf16x8*)(p);
        bf16x8 u1 = *(const bf16x8*)(p + 8);
        const float* sp = scale + b * CC + c0 + coff;
        f32x4 s0 = *(const f32x4*)(sp), s1 = *(const f32x4*)(sp + 4);
        f32x4 s2 = *(const f32x4*)(sp + 8), s3 = *(const f32x4*)(sp + 12);
#pragma unroll
        for (int j = 0; j < 4; ++j) {
            TT[(coff + j)      * 68 + hw_r] = (float)u0[j]     * s0[j];
            TT[(coff + 4 + j)  * 68 + hw_r] = (float)u0[4 + j] * s1[j];
            TT[(coff + 8 + j)  * 68 + hw_r] = (float)u1[j]     * s2[j];
            TT[(coff + 12 + j) * 68 + hw_r] = (float)u1[4 + j] * s3[j];
        }
    }
    __syncthreads();
    {
        const int c_r   = t >> 2;
        const int hwoff = (t & 3) * 16;
        const size_t go = ((size_t)b * CC + c0 + c_r) * HWSZ + hw0 + hwoff;
#pragma unroll
        for (int v = 0; v < 4; ++v) {
            f32x4 tv = *(const f32x4*)(&TT[c_r * 68 + hwoff + v * 4]);
            f32x4 xv = *(const f32x4*)(x + go + v * 4);
#pragma unroll
            for (int j = 0; j < 4; ++j) tv[j] += xv[j];
            *(f32x4*)(out + go + v * 4) = tv;
        }
    }
}

// ---------------------------------------------------------------------------
extern "C" void kernel_launch(void* const* d_in, const int* in_sizes, int n_in,
                              void* d_out, int out_size, void* d_ws, size_t ws_size,
                              hipStream_t stream)
{
    const float* x      = (const float*)d_in[0];
    const float* pw1_w  = (const float*)d_in[1];
    const float* xy3_w  = (const float*)d_in[2];
    const float* xy5_w  = (const float*)d_in[3];
    const float* bnxy_g = (const float*)d_in[4];
    const float* bnxy_b = (const float*)d_in[5];
    const float* bnxy_m = (const float*)d_in[6];
    const float* bnxy_v = (const float*)d_in[7];
    const float* xz3_w  = (const float*)d_in[8];
    const float* xz5_w  = (const float*)d_in[9];
    const float* bnxz_g = (const float*)d_in[10];
    const float* bnxz_b = (const float*)d_in[11];
    const float* bnxz_m = (const float*)d_in[12];
    const float* bnxz_v = (const float*)d_in[13];
    const float* yz3_w  = (const float*)d_in[14];
    const float* yz5_w  = (const float*)d_in[15];
    const float* bnyz_g = (const float*)d_in[16];
    const float* bnyz_b = (const float*)d_in[17];
    const float* bnyz_m = (const float*)d_in[18];
    const float* bnyz_v = (const float*)d_in[19];
    const float* alpha  = (const float*)d_in[20];
    const float* beta   = (const float*)d_in[21];
    const float* pw2_w  = (const float*)d_in[22];
    const float* bn2_g  = (const float*)d_in[23];
    const float* bn2_b  = (const float*)d_in[24];
    const float* bn2_m  = (const float*)d_in[25];
    const float* bn2_v  = (const float*)d_in[26];
    const float* fc1_w  = (const float*)d_in[27];
    const float* fc1_b  = (const float*)d_in[28];
    const float* fc2_w  = (const float*)d_in[29];
    const float* fc2_b  = (const float*)d_in[30];

    const size_t NEL = (size_t)BB * CC * HWSZ;   // 12,845,056
    char* ws = (char*)d_ws;
    float* scale = (float*)(ws + OFF_SCALE);
    float* sums  = (float*)(ws + OFF_SUMS);
    bf16*  wbf1  = (bf16*) (ws + OFF_WBF1);
    bf16*  wbf2  = (bf16*) (ws + OFF_WBF2);
    bf16*  wdw   = (bf16*) (ws + OFF_WDW);
    float* bnc   = (float*)(ws + OFF_BNC);
    bf16*  out2  = (bf16*) (ws + OFF_OUT2);
    bf16*  mid   = (bf16*)d_out;           // d_out as scratch: mid | top
    bf16*  top   = (bf16*)d_out + NEL;

    precast<<<257, 256, 0, stream>>>(pw1_w, pw2_w,
        xy3_w, xy5_w, xz3_w, xz5_w, yz3_w, yz5_w,
        bnxy_g, bnxy_b, bnxy_m, bnxy_v,
        bnxz_g, bnxz_b, bnxz_m, bnxz_v,
        bnyz_g, bnyz_b, bnyz_m, bnyz_v,
        alpha, beta, wbf1, wbf2, wdw, bnc, sums);

    pw_gemm1<<<dim3(49, 16), 256, 0, stream>>>(x, wbf1, mid);
    dwfuse<<<dim3(7, 28, 16), 256, 0, stream>>>(mid, wdw, bnc, top);
    pw_gemm2<<<dim3(49, 16), 256, 0, stream>>>(top, wbf2, bn2_g, bn2_b,
                                               bn2_m, bn2_v, out2, sums);
    se_fc<<<BB, 256, 0, stream>>>(sums, fc1_w, fc1_b, fc2_w, fc2_b, scale);
    se_apply<<<dim3(49, 4, 16), 256, 0, stream>>>(out2, x, scale, (float*)d_out);
}

// Round 7
// 295.079 us; speedup vs baseline: 1.2967x; 1.0887x over previous
//
#include <hip/hip_runtime.h>
#include <math.h>

typedef __bf16 bf16;
typedef __bf16 bf16x8 __attribute__((ext_vector_type(8)));
typedef __bf16 bf16x4 __attribute__((ext_vector_type(4)));
typedef float f32x4 __attribute__((ext_vector_type(4)));

#define CC 256
#define BB 16
#define HH 56
#define WW 56
#define HWSZ 3136   // 56*56
#define EPS 1e-5f

// ws byte offsets
#define OFF_SCALE 0
#define OFF_SUMS  16384
#define OFF_WBF1  32768
#define OFF_WBF2  163840
#define OFF_WDW   294912        // 35*256 bf16 (wcomb 25 | wxz 5 | wyz 5)
#define OFF_BNC   312832        // 8*256 f32
#define OFF_OUT2  321024        // NEL bf16

// ---------------------------------------------------------------------------
// K0: precast weights -> bf16, combined DW taps + BN consts, zero sums.
// ---------------------------------------------------------------------------
__global__ __launch_bounds__(256) void precast(
    const float* __restrict__ w1, const float* __restrict__ w2,
    const float* __restrict__ xy3, const float* __restrict__ xy5,
    const float* __restrict__ xz3, const float* __restrict__ xz5,
    const float* __restrict__ yz3, const float* __restrict__ yz5,
    const float* __restrict__ gxy, const float* __restrict__ bxy,
    const float* __restrict__ mxy, const float* __restrict__ vxy,
    const float* __restrict__ gxz, const float* __restrict__ bxz,
    const float* __restrict__ mxz, const float* __restrict__ vxz,
    const float* __restrict__ gyz, const float* __restrict__ byz,
    const float* __restrict__ myz, const float* __restrict__ vyz,
    const float* __restrict__ alpha, const float* __restrict__ beta,
    bf16* __restrict__ wbf1, bf16* __restrict__ wbf2,
    bf16* __restrict__ wdw, float* __restrict__ bnc,
    float* __restrict__ sums)
{
    const int blk = blockIdx.x, t = threadIdx.x;
    if (blk < 128) {
        int i = blk * 512 + t * 2;
        wbf1[i] = (bf16)w1[i]; wbf1[i + 1] = (bf16)w1[i + 1];
    } else if (blk < 256) {
        int i = (blk - 128) * 512 + t * 2;
        wbf2[i] = (bf16)w2[i]; wbf2[i + 1] = (bf16)w2[i + 1];
    } else {
        const int c = t;
#pragma unroll
        for (int dh = 0; dh < 5; ++dh)
#pragma unroll
            for (int dw = 0; dw < 5; ++dw) {
                float v = xy5[c * 25 + dh * 5 + dw];
                if (dh >= 1 && dh <= 3 && dw >= 1 && dw <= 3)
                    v += xy3[c * 9 + (dh - 1) * 3 + (dw - 1)];
                wdw[(dh * 5 + dw) * CC + c] = (bf16)v;
            }
#pragma unroll
        for (int d = 0; d < 5; ++d) {
            float v = xz5[c * 5 + d];
            if (d >= 1 && d <= 3) v += xz3[c * 3 + d - 1];
            wdw[(25 + d) * CC + c] = (bf16)v;
            float u = yz5[c * 5 + d];
            if (d >= 1 && d <= 3) u += yz3[c * 3 + d - 1];
            wdw[(30 + d) * CC + c] = (bf16)u;
        }
        float s;
        s = gxy[c] * rsqrtf(vxy[c] + EPS); bnc[0*CC+c] = s; bnc[1*CC+c] = bxy[c] - mxy[c]*s;
        s = gxz[c] * rsqrtf(vxz[c] + EPS); bnc[2*CC+c] = s; bnc[3*CC+c] = bxz[c] - mxz[c]*s;
        s = gyz[c] * rsqrtf(vyz[c] + EPS); bnc[4*CC+c] = s; bnc[5*CC+c] = byz[c] - myz[c]*s;
        bnc[6*CC+c] = alpha[c]; bnc[7*CC+c] = beta[c];
        for (int i = t; i < BB * CC; i += 256) sums[i] = 0.f;
    }
}

// ---------------------------------------------------------------------------
// K1: pw1 GEMM.  mid[b][hw][co] = sum_ci x[b][ci][hw] * w[co][ci]  (bf16 out)
// Weights fully preloaded to registers BEFORE staging (L2 latency overlaps).
// Block: 64 hw x 256 co, 4 waves. grid (49, 16).
// ---------------------------------------------------------------------------
__global__ __launch_bounds__(256, 2) void pw_gemm1(
    const float* __restrict__ in, const bf16* __restrict__ wbf,
    bf16* __restrict__ mid)
{
    __shared__ __align__(16) bf16 XT[64][264];   // [hw][ci], pad 264
    const int hw0 = blockIdx.x * 64;
    const int b   = blockIdx.y;
    const int t   = threadIdx.x;
    const int lane = t & 63, wv = t >> 6;
    const int q = lane >> 4, n = lane & 15;
    const int co_w = wv * 64;

    // 1) preload all A-fragments (weights) into registers
    bf16x8 aq[4][8];
#pragma unroll
    for (int cf = 0; cf < 4; ++cf) {
        const bf16* wp = wbf + (size_t)(co_w + cf * 16 + n) * CC + q * 8;
#pragma unroll
        for (int kk = 0; kk < 8; ++kk)
            aq[cf][kk] = *(const bf16x8*)(wp + kk * 32);
    }

    {   // 2) stage x tile (fp32 NCHW) -> XT[hw][ci] bf16
        const int hwg = (t & 15) * 4;
        const int cig = (t >> 4) * 4;
        const float* base = in + (size_t)b * CC * HWSZ + hw0 + hwg;
#pragma unroll
        for (int pass = 0; pass < 4; ++pass) {
            const int ci0 = pass * 64 + cig;
            f32x4 v[4];
#pragma unroll
            for (int i = 0; i < 4; ++i)
                v[i] = *(const f32x4*)(base + (size_t)(ci0 + i) * HWSZ);
#pragma unroll
            for (int j = 0; j < 4; ++j) {
                bf16x4 r = {(bf16)v[0][j], (bf16)v[1][j], (bf16)v[2][j], (bf16)v[3][j]};
                *(bf16x4*)(&XT[hwg + j][ci0]) = r;
            }
        }
    }
    __syncthreads();

    // 3) K-loop: LDS + MFMA only
    f32x4 acc[4][4] = {};   // [cf][hf]
#pragma unroll
    for (int kk = 0; kk < 8; ++kk) {
        bf16x8 bq[4];
#pragma unroll
        for (int hf = 0; hf < 4; ++hf)
            bq[hf] = *(const bf16x8*)(&XT[hf * 16 + n][kk * 32 + q * 8]);
#pragma unroll
        for (int cf = 0; cf < 4; ++cf)
#pragma unroll
            for (int hf = 0; hf < 4; ++hf)
                acc[cf][hf] = __builtin_amdgcn_mfma_f32_16x16x32_bf16(
                    aq[cf][kk], bq[hf], acc[cf][hf], 0, 0, 0);
    }

    bf16* ob = mid + ((size_t)b * HWSZ + hw0) * CC;
#pragma unroll
    for (int cf = 0; cf < 4; ++cf) {
        const int co4 = co_w + cf * 16 + q * 4;
#pragma unroll
        for (int hf = 0; hf < 4; ++hf) {
            bf16x4 r = {(bf16)acc[cf][hf][0], (bf16)acc[cf][hf][1],
                        (bf16)acc[cf][hf][2], (bf16)acc[cf][hf][3]};
            *(bf16x4*)(ob + (size_t)(hf * 16 + n) * CC + co4) = r;
        }
    }
}

// ---------------------------------------------------------------------------
// K2: fused depthwise + BN + ReLU + gate, NHWC. 2 h-rows per thread.
// Weights in LDS duplicated x2 -> wave64 b128 reads are lane-linear
// (conflict-free). BN consts read from global (L1-cached) in epilogue.
// grid (7, 28, 16); block 256 = 8 w x 32 c-groups.
// ---------------------------------------------------------------------------
__global__ __launch_bounds__(256) void dwfuse(
    const bf16* __restrict__ mid, const bf16* __restrict__ wdw,
    const float* __restrict__ bnc, bf16* __restrict__ top)
{
    __shared__ __align__(16) bf16 lw2[35 * 512];   // 35 rows x 1KB (dup x2)
    const int t = threadIdx.x;
    for (int idx = t; idx < 35 * 64; idx += 256) {
        const int tap = idx >> 6, slot = idx & 63;
        *(bf16x8*)(&lw2[tap * 512 + slot * 8]) =
            *(const bf16x8*)(wdw + tap * 256 + (slot & 31) * 8);
    }
    __syncthreads();

    const int w  = blockIdx.x * 8 + (t >> 5);
    const int h0 = blockIdx.y * 2;
    const int bb = blockIdx.z;
    const int c0 = (t & 31) * 8;
    const int ls = (t & 63) * 8;             // lane-linear slot in lw2 rows
    const size_t plane = (size_t)bb * HWSZ;

    float axy[2][8] = {}, axz[2][8] = {}, ayz[2][8] = {};
#pragma unroll
    for (int dhh = 0; dhh < 6; ++dhh) {          // hh = h0-2+dhh
        const int hh = h0 - 2 + dhh;
        if ((unsigned)hh >= (unsigned)HH) continue;
#pragma unroll
        for (int dw = 0; dw < 5; ++dw) {
            const int ww = w + dw - 2;
            if ((unsigned)ww >= (unsigned)WW) continue;
            bf16x8 v = *(const bf16x8*)(mid + ((plane + hh * WW + ww) * CC + c0));
            float fv[8];
#pragma unroll
            for (int j = 0; j < 8; ++j) fv[j] = (float)v[j];
#pragma unroll
            for (int p = 0; p < 2; ++p) {
                const int dh = dhh - p;          // tap row for pixel h0+p
                if (dh < 0 || dh > 4) continue;  // compile-time
                bf16x8 wc = *(const bf16x8*)(&lw2[(dh * 5 + dw) * 512 + ls]);
#pragma unroll
                for (int j = 0; j < 8; ++j) axy[p][j] += (float)wc[j] * fv[j];
                if (dh == 2) {
                    bf16x8 wz = *(const bf16x8*)(&lw2[(25 + dw) * 512 + ls]);
#pragma unroll
                    for (int j = 0; j < 8; ++j) axz[p][j] += (float)wz[j] * fv[j];
                }
                if (dw == 2) {
                    bf16x8 wy = *(const bf16x8*)(&lw2[(30 + dh) * 512 + ls]);
#pragma unroll
                    for (int j = 0; j < 8; ++j) ayz[p][j] += (float)wy[j] * fv[j];
                }
            }
        }
    }

    // BN consts from global, vector loads (L1-cached, tiny)
    float bnv[8][8];
#pragma unroll
    for (int k = 0; k < 8; ++k) {
        f32x4 a0 = *(const f32x4*)(bnc + k * CC + c0);
        f32x4 a1 = *(const f32x4*)(bnc + k * CC + c0 + 4);
#pragma unroll
        for (int j = 0; j < 4; ++j) { bnv[k][j] = a0[j]; bnv[k][4 + j] = a1[j]; }
    }

#pragma unroll
    for (int p = 0; p < 2; ++p) {
        bf16x8 r;
#pragma unroll
        for (int j = 0; j < 8; ++j) {
            const float fxy = fmaxf(axy[p][j] * bnv[0][j] + bnv[1][j], 0.f);
            const float fxz = fmaxf(axz[p][j] * bnv[2][j] + bnv[3][j], 0.f);
            const float fyz = fmaxf(ayz[p][j] * bnv[4][j] + bnv[5][j], 0.f);
            const float z   = bnv[6][j] * fxz + bnv[7][j] * fyz;
            const float g   = 1.f / (1.f + expf(-z));
            r[j] = (bf16)fmaxf(fxy * g, 0.f);
        }
        *(bf16x8*)(top + ((plane + (h0 + p) * WW + w) * CC + c0)) = r;
    }
}

// ---------------------------------------------------------------------------
// K3: pw2 GEMM + BN + ReLU + SE partial sums.  Same frame as K1.
// ---------------------------------------------------------------------------
__global__ __launch_bounds__(256, 2) void pw_gemm2(
    const bf16* __restrict__ top, const bf16* __restrict__ wbf,
    const float* __restrict__ g2, const float* __restrict__ b2,
    const float* __restrict__ m2, const float* __restrict__ v2,
    bf16* __restrict__ out2, float* __restrict__ sums)
{
    __shared__ __align__(16) bf16 XT[64][264];
    const int hw0 = blockIdx.x * 64;
    const int b   = blockIdx.y;
    const int t   = threadIdx.x;
    const int lane = t & 63, wv = t >> 6;
    const int q = lane >> 4, n = lane & 15;
    const int co_w = wv * 64;

    bf16x8 aq[4][8];
#pragma unroll
    for (int cf = 0; cf < 4; ++cf) {
        const bf16* wp = wbf + (size_t)(co_w + cf * 16 + n) * CC + q * 8;
#pragma unroll
        for (int kk = 0; kk < 8; ++kk)
            aq[cf][kk] = *(const bf16x8*)(wp + kk * 32);
    }

    {   // straight copy staging (already NHWC): 64 bf16 per thread
        const int hw_r = t >> 2;
        const int k0   = (t & 3) * 64;
        const bf16* src = top + ((size_t)b * HWSZ + hw0 + hw_r) * CC + k0;
#pragma unroll
        for (int j = 0; j < 8; ++j)
            *(bf16x8*)(&XT[hw_r][k0 + j * 8]) = *(const bf16x8*)(src + j * 8);
    }
    __syncthreads();

    f32x4 acc[4][4] = {};
#pragma unroll
    for (int kk = 0; kk < 8; ++kk) {
        bf16x8 bq[4];
#pragma unroll
        for (int hf = 0; hf < 4; ++hf)
            bq[hf] = *(const bf16x8*)(&XT[hf * 16 + n][kk * 32 + q * 8]);
#pragma unroll
        for (int cf = 0; cf < 4; ++cf)
#pragma unroll
            for (int hf = 0; hf < 4; ++hf)
                acc[cf][hf] = __builtin_amdgcn_mfma_f32_16x16x32_bf16(
                    aq[cf][kk], bq[hf], acc[cf][hf], 0, 0, 0);
    }

    bf16* ob = out2 + ((size_t)b * HWSZ + hw0) * CC;
#pragma unroll
    for (int cf = 0; cf < 4; ++cf) {
        const int co4 = co_w + cf * 16 + q * 4;
        f32x4 g = *(const f32x4*)(g2 + co4);
        f32x4 bb = *(const f32x4*)(b2 + co4);
        f32x4 mm = *(const f32x4*)(m2 + co4);
        f32x4 vv = *(const f32x4*)(v2 + co4);
        f32x4 sc, sh;
#pragma unroll
        for (int r = 0; r < 4; ++r) {
            sc[r] = g[r] * rsqrtf(vv[r] + EPS);
            sh[r] = bb[r] - mm[r] * sc[r];
        }
        f32x4 rs = {};
#pragma unroll
        for (int hf = 0; hf < 4; ++hf) {
            bf16x4 r4;
#pragma unroll
            for (int r = 0; r < 4; ++r) {
                float v = fmaxf(acc[cf][hf][r] * sc[r] + sh[r], 0.f);
                rs[r] += v;
                r4[r] = (bf16)v;
            }
            *(bf16x4*)(ob + (size_t)(hf * 16 + n) * CC + co4) = r4;
        }
        // reduce over the 16 lanes (n) sharing this (q, co4)
#pragma unroll
        for (int msk = 1; msk < 16; msk <<= 1)
#pragma unroll
            for (int r = 0; r < 4; ++r) rs[r] += __shfl_xor(rs[r], msk);
        if (n == 0) {
#pragma unroll
            for (int r = 0; r < 4; ++r)
                atomicAdd(&sums[b * CC + co4 + r], rs[r]);
        }
    }
}

// ---------------------------------------------------------------------------
// K4: SE fully-connected: scale[b,c] = sigmoid(W2 relu(W1 mean + b1) + b2)
// ---------------------------------------------------------------------------
__global__ __launch_bounds__(256) void se_fc(
    const float* __restrict__ sums,
    const float* __restrict__ w1, const float* __restrict__ b1,
    const float* __restrict__ w2, const float* __restrict__ b2,
    float* __restrict__ scale)
{
    __shared__ float mean[256];
    __shared__ float hid[16];
    const int b = blockIdx.x, tid = threadIdx.x;
    mean[tid] = sums[b * CC + tid] * (1.f / (float)HWSZ);
    __syncthreads();
    if (tid < 16) {
        float h = b1[tid];
        for (int cd = 0; cd < 256; ++cd) h += w1[tid * 256 + cd] * mean[cd];
        hid[tid] = fmaxf(h, 0.f);
    }
    __syncthreads();
    float v = b2[tid];
#pragma unroll
    for (int md = 0; md < 16; ++md) v += w2[tid * 16 + md] * hid[md];
    scale[b * CC + tid] = 1.f / (1.f + expf(-v));
}

// ---------------------------------------------------------------------------
// K5: out[b][c][hw] = out2[b][hw][c] * scale[b,c] + x[b][c][hw]
// 64x64 LDS tile transpose.  grid (49, 4, 16).
// ---------------------------------------------------------------------------
__global__ __launch_bounds__(256) void se_apply(
    const bf16* __restrict__ out2, const float* __restrict__ x,
    const float* __restrict__ scale, float* __restrict__ out)
{
    __shared__ float TT[64 * 68];   // [c_local][hw_local], pad 68
    const int hw0 = blockIdx.x * 64;
    const int c0  = blockIdx.y * 64;
    const int b   = blockIdx.z;
    const int t   = threadIdx.x;

    {
        const int hw_r = t >> 2;
        const int coff = (t & 3) * 16;
        const bf16* p = out2 + ((size_t)b * HWSZ + hw0 + hw_r) * CC + c0 + coff;
        bf16x8 u0 = *(const bf16x8*)(p);
        bf16x8 u1 = *(const bf16x8*)(p + 8);
        const float* sp = scale + b * CC + c0 + coff;
        f32x4 s0 = *(const f32x4*)(sp), s1 = *(const f32x4*)(sp + 4);
        f32x4 s2 = *(const f32x4*)(sp + 8), s3 = *(const f32x4*)(sp + 12);
#pragma unroll
        for (int j = 0; j < 4; ++j) {
            TT[(coff + j)      * 68 + hw_r] = (float)u0[j]     * s0[j];
            TT[(coff + 4 + j)  * 68 + hw_r] = (float)u0[4 + j] * s1[j];
            TT[(coff + 8 + j)  * 68 + hw_r] = (float)u1[j]     * s2[j];
            TT[(coff + 12 + j) * 68 + hw_r] = (float)u1[4 + j] * s3[j];
        }
    }
    __syncthreads();
    {
        const int c_r   = t >> 2;
        const int hwoff = (t & 3) * 16;
        const size_t go = ((size_t)b * CC + c0 + c_r) * HWSZ + hw0 + hwoff;
#pragma unroll
        for (int v = 0; v < 4; ++v) {
            f32x4 tv = *(const f32x4*)(&TT[c_r * 68 + hwoff + v * 4]);
            f32x4 xv = *(const f32x4*)(x + go + v * 4);
#pragma unroll
            for (int j = 0; j < 4; ++j) tv[j] += xv[j];
            *(f32x4*)(out + go + v * 4) = tv;
        }
    }
}

// ---------------------------------------------------------------------------
extern "C" void kernel_launch(void* const* d_in, const int* in_sizes, int n_in,
                              void* d_out, int out_size, void* d_ws, size_t ws_size,
                              hipStream_t stream)
{
    const float* x      = (const float*)d_in[0];
    const float* pw1_w  = (const float*)d_in[1];
    const float* xy3_w  = (const float*)d_in[2];
    const float* xy5_w  = (const float*)d_in[3];
    const float* bnxy_g = (const float*)d_in[4];
    const float* bnxy_b = (const float*)d_in[5];
    const float* bnxy_m = (const float*)d_in[6];
    const float* bnxy_v = (const float*)d_in[7];
    const float* xz3_w  = (const float*)d_in[8];
    const float* xz5_w  = (const float*)d_in[9];
    const float* bnxz_g = (const float*)d_in[10];
    const float* bnxz_b = (const float*)d_in[11];
    const float* bnxz_m = (const float*)d_in[12];
    const float* bnxz_v = (const float*)d_in[13];
    const float* yz3_w  = (const float*)d_in[14];
    const float* yz5_w  = (const float*)d_in[15];
    const float* bnyz_g = (const float*)d_in[16];
    const float* bnyz_b = (const float*)d_in[17];
    const float* bnyz_m = (const float*)d_in[18];
    const float* bnyz_v = (const float*)d_in[19];
    const float* alpha  = (const float*)d_in[20];
    const float* beta   = (const float*)d_in[21];
    const float* pw2_w  = (const float*)d_in[22];
    const float* bn2_g  = (const float*)d_in[23];
    const float* bn2_b  = (const float*)d_in[24];
    const float* bn2_m  = (const float*)d_in[25];
    const float* bn2_v  = (const float*)d_in[26];
    const float* fc1_w  = (const float*)d_in[27];
    const float* fc1_b  = (const float*)d_in[28];
    const float* fc2_w  = (const float*)d_in[29];
    const float* fc2_b  = (const float*)d_in[30];

    const size_t NEL = (size_t)BB * CC * HWSZ;   // 12,845,056
    char* ws = (char*)d_ws;
    float* scale = (float*)(ws + OFF_SCALE);
    float* sums  = (float*)(ws + OFF_SUMS);
    bf16*  wbf1  = (bf16*) (ws + OFF_WBF1);
    bf16*  wbf2  = (bf16*) (ws + OFF_WBF2);
    bf16*  wdw   = (bf16*) (ws + OFF_WDW);
    float* bnc   = (float*)(ws + OFF_BNC);
    bf16*  out2  = (bf16*) (ws + OFF_OUT2);
    bf16*  mid   = (bf16*)d_out;           // d_out as scratch: mid | top
    bf16*  top   = (bf16*)d_out + NEL;

    precast<<<257, 256, 0, stream>>>(pw1_w, pw2_w,
        xy3_w, xy5_w, xz3_w, xz5_w, yz3_w, yz5_w,
        bnxy_g, bnxy_b, bnxy_m, bnxy_v,
        bnxz_g, bnxz_b, bnxz_m, bnxz_v,
        bnyz_g, bnyz_b, bnyz_m, bnyz_v,
        alpha, beta, wbf1, wbf2, wdw, bnc, sums);

    pw_gemm1<<<dim3(49, 16), 256, 0, stream>>>(x, wbf1, mid);
    dwfuse<<<dim3(7, 28, 16), 256, 0, stream>>>(mid, wdw, bnc, top);
    pw_gemm2<<<dim3(49, 16), 256, 0, stream>>>(top, wbf2, bn2_g, bn2_b,
                                               bn2_m, bn2_v, out2, sums);
    se_fc<<<BB, 256, 0, stream>>>(sums, fc1_w, fc1_b, fc2_w, fc2_b, scale);
    se_apply<<<dim3(49, 4, 16), 256, 0, stream>>>(out2, x, scale, (float*)d_out);
}